// Round 12
// baseline (334.467 us; speedup 1.0000x reference)
//
#include <hip/hip_runtime.h>
#include <math.h>

#define N_NODES 50000
#define N_EDGES 800000
#define NUM_GRAPHS_ 128
#define SCAN_NB 98   // ceil(50000/512)
#define HCHUNKS 128
#define EDGES_PER_CHUNK 6250 // 800000/128
#define HWORDS2 25000        // 50000 nodes, 2 packed u16 per word
#define TS_B 391             // scan_chunks blocks: ceil(25000/64)

typedef unsigned short u16;
typedef unsigned int u32;
typedef __attribute__((ext_vector_type(8))) short bf16x8;   // 8 bf16 (4 VGPRs)
typedef __attribute__((ext_vector_type(4))) float f32x4;    // 4 fp32

__device__ __forceinline__ float elu_f(float v) {
    return v > 0.f ? v : (__expf(v) - 1.f);
}
__device__ __forceinline__ u16 f2bf(float f) {  // RNE
    u32 u = __float_as_uint(f);
    u += 0x7FFFu + ((u >> 16) & 1u);
    return (u16)(u >> 16);
}
__device__ __forceinline__ float bf2f(u16 h) {
    return __uint_as_float(((u32)h) << 16);
}
__device__ __forceinline__ void bfpair(u32 v, float& lo, float& hi) {
    lo = __uint_as_float(v << 16);
    hi = __uint_as_float(v & 0xFFFF0000u);
}
__device__ __forceinline__ u32 packbf(float lo, float hi) {
    return (u32)f2bf(lo) | ((u32)f2bf(hi) << 16);
}

// ---------------------------------------------------------------------------
// Gather core, 8 lanes/row (uint4 = 16B/lane), 8 edge-groups, 2-deep.
// ---------------------------------------------------------------------------
__device__ __forceinline__ void gather_rows8(
    const int2* __restrict__ csr, const uint4* __restrict__ x4,
    int beg, int end, int eg, int cg,
    float* acc, float& WS) {
    float A[8], B[8];
#pragma unroll
    for (int j = 0; j < 8; j++) { A[j] = 0.f; B[j] = 0.f; }
    float ws0 = 0.f, ws1 = 0.f;
    int p = beg + eg;
    for (; p + 8 < end; p += 16) {
        int2 e0 = csr[p];
        int2 e1 = csr[p + 8];
        uint4 v0 = x4[(size_t)e0.x * 8 + cg];
        uint4 v1 = x4[(size_t)e1.x * 8 + cg];
        float w0 = __int_as_float(e0.y);
        float w1 = __int_as_float(e1.y);
        float f0, f1;
        bfpair(v0.x, f0, f1); A[0] += w0 * f0; A[1] += w0 * f1;
        bfpair(v0.y, f0, f1); A[2] += w0 * f0; A[3] += w0 * f1;
        bfpair(v0.z, f0, f1); A[4] += w0 * f0; A[5] += w0 * f1;
        bfpair(v0.w, f0, f1); A[6] += w0 * f0; A[7] += w0 * f1;
        ws0 += w0;
        bfpair(v1.x, f0, f1); B[0] += w1 * f0; B[1] += w1 * f1;
        bfpair(v1.y, f0, f1); B[2] += w1 * f0; B[3] += w1 * f1;
        bfpair(v1.z, f0, f1); B[4] += w1 * f0; B[5] += w1 * f1;
        bfpair(v1.w, f0, f1); B[6] += w1 * f0; B[7] += w1 * f1;
        ws1 += w1;
    }
    if (p < end) {
        int2 e0 = csr[p];
        uint4 v0 = x4[(size_t)e0.x * 8 + cg];
        float w0 = __int_as_float(e0.y);
        float f0, f1;
        bfpair(v0.x, f0, f1); A[0] += w0 * f0; A[1] += w0 * f1;
        bfpair(v0.y, f0, f1); A[2] += w0 * f0; A[3] += w0 * f1;
        bfpair(v0.z, f0, f1); A[4] += w0 * f0; A[5] += w0 * f1;
        bfpair(v0.w, f0, f1); A[6] += w0 * f0; A[7] += w0 * f1;
        ws0 += w0;
    }
#pragma unroll
    for (int j = 0; j < 8; j++) acc[j] = A[j] + B[j];
    WS = ws0 + ws1;
}

// ---------------------------------------------------------------------------
// Fused prep: blocks [0,3125) edge weights + dst16; [3125,6250) x->bf16;
// [6250,6280) weight packing.
// ---------------------------------------------------------------------------
__global__ void prep_kernel(const float* __restrict__ edge_attr,
                            const float* __restrict__ w_fc1,
                            const float* __restrict__ b_fc1,
                            const int* __restrict__ edge_index,
                            float* __restrict__ ew,
                            u16* __restrict__ dst16,
                            const float* __restrict__ x, u16* __restrict__ xb,
                            const float* __restrict__ w3_0, const float* __restrict__ w1_0, const float* __restrict__ w2_0,
                            const float* __restrict__ w3_1, const float* __restrict__ w1_1, const float* __restrict__ w2_1,
                            const float* __restrict__ w3_2, const float* __restrict__ w1_2, const float* __restrict__ w2_2,
                            u16* __restrict__ bp0, u16* __restrict__ bp1, u16* __restrict__ bp2) {
    const int b = blockIdx.x;
    if (b < 3125) {
        const int e = b * 256 + threadIdx.x;
        const float4* ea = (const float4*)(edge_attr + (size_t)e * 16);
        const float4* wf = (const float4*)w_fc1;
        float acc = b_fc1[0];
#pragma unroll
        for (int i = 0; i < 4; i++) {
            float4 a = ea[i], w = wf[i];
            acc += a.x * w.x + a.y * w.y + a.z * w.z + a.w * w.w;
        }
        ew[e] = acc;
        dst16[e] = (u16)edge_index[N_EDGES + e];
    } else if (b < 6250) {
        const int g = (b - 3125) * 256 + threadIdx.x;
        float4 v = ((const float4*)x)[g];
        uint2 o;
        o.x = packbf(v.x, v.y);
        o.y = packbf(v.z, v.w);
        ((uint2*)xb)[g] = o;
    } else {
        const int t = (b - 6250) * 256 + threadIdx.x;
        u16 buf[8];
        if (t < 4608) {
            int DOUT, lid;
            const float *w3, *w1, *w2;
            u16* bp;
            if (t < 1536) { DOUT = 64;  lid = t;        w3 = w3_0; w1 = w1_0; w2 = w2_0; bp = bp0; }
            else          { DOUT = 128; lid = t - 1536; w3 = w3_1; w1 = w1_1; w2 = w2_1; bp = bp1; }
            const int NT = DOUT / 16;
            const int lane = lid & 63;
            const int fragid = lid >> 6;
            const int chunk = fragid / NT;
            const int ntile = fragid % NT;
            const int n = ntile * 16 + (lane & 15);
            const int kbase = chunk * 32 + (lane >> 4) * 8;
#pragma unroll
            for (int j = 0; j < 8; j++) {
                int k = kbase + j;
                int region = k / 64;
                int kk = k - region * 64;
                float v = (region == 0) ? w3[kk * DOUT + n]
                        : (region == 1) ? w1[kk * DOUT + n]
                                        : -w2[kk * DOUT + n];
                buf[j] = f2bf(v);
            }
            *(bf16x8*)(bp + ((size_t)lid << 3)) = *(bf16x8*)buf;
        } else if (t < 7680) {
            const int lid = t - 4608;          // 0..3071
            const int NT = 12;
            const int lane = lid & 63;
            const int fragid = lid >> 6;       // 0..47
            const int chunk = fragid / NT;     // 0..3
            const int ntile = fragid % NT;     // 0..11
            const int n = ntile * 16 + (lane & 15);   // 0..191
            const int kbase = chunk * 32 + (lane >> 4) * 8;  // 0..127
#pragma unroll
            for (int j = 0; j < 8; j++) {
                int k = kbase + j;
                float v = (n < 64)  ? w3_2[k * 64 + n]
                        : (n < 128) ? -w2_2[k * 64 + (n - 64)]
                                    : w1_2[k * 64 + (n - 128)];
                buf[j] = f2bf(v);
            }
            *(bf16x8*)(bp2 + ((size_t)lid << 3)) = *(bf16x8*)buf;
        }
    }
}

// ---------------------------------------------------------------------------
// Degree histogram, SINGLE pass per chunk: 1024 threads, full 100KB packed
// bins (u16 pairs). No half-split, no discarded lanes, coalesced reads.
// partial layout: [chunk c][word g] = counts of nodes 2g, 2g+1 in chunk c.
// ---------------------------------------------------------------------------
__global__ __launch_bounds__(1024) void deg_hist_kernel(const u16* __restrict__ dst16,
                                                        u32* __restrict__ partial) {
    __shared__ u32 bins[HWORDS2];
    const int c = blockIdx.x;
    const int t = threadIdx.x;
    for (int i = t; i < HWORDS2; i += 1024) bins[i] = 0;
    __syncthreads();
    const int base = c * EDGES_PER_CHUNK;
    for (int i = t; i < EDGES_PER_CHUNK; i += 1024) {
        const int d = (int)dst16[base + i];
        atomicAdd(&bins[d >> 1], 1u << ((d & 1) * 16));
    }
    __syncthreads();
    u32* outp = partial + (size_t)c * HWORDS2;
    for (int i = t; i < HWORDS2; i += 1024) outp[i] = bins[i];
}

// ---------------------------------------------------------------------------
// Exclusive scan along the chunk axis, register-parallel (32 chunks/thread).
// partial[c][g] layout. 391 blocks x 256 threads (64 words x 4 quarters).
// ---------------------------------------------------------------------------
__global__ __launch_bounds__(256) void scan_chunks_kernel(const u32* __restrict__ partial,
                                                          u32* __restrict__ prefpack,
                                                          u32* __restrict__ degpack) {
    __shared__ u32 qsums[4][64];
    const int t = threadIdx.x;
    const int wl = t & 63;
    const int cq = t >> 6;           // quarter: chunks [cq*32, cq*32+32)
    const int g = blockIdx.x * 64 + wl;
    const bool ok = g < HWORDS2;

    u32 vals[32];
#pragma unroll
    for (int i = 0; i < 32; i++) {
        const int c = cq * 32 + i;
        vals[i] = ok ? partial[(size_t)c * HWORDS2 + g] : 0u;
    }
    u32 s = 0;
#pragma unroll
    for (int i = 0; i < 32; i++) s += vals[i];   // packed add, no carry (deg << 65536)
    qsums[cq][wl] = s;
    __syncthreads();
    u32 run = 0;
#pragma unroll
    for (int j = 0; j < 4; j++)
        if (j < cq) run += qsums[j][wl];

    if (ok) {
#pragma unroll
        for (int i = 0; i < 32; i++) {
            const int c = cq * 32 + i;
            prefpack[(size_t)c * HWORDS2 + g] = run;
            run += vals[i];
        }
        if (cq == 3) degpack[g] = run;
    }
}

// ---------------------------------------------------------------------------
// Hierarchical exclusive scan of degpack -> rowptr[N+1]
// ---------------------------------------------------------------------------
__global__ __launch_bounds__(256) void scan1_kernel(const u32* __restrict__ degpack,
                                                    int* __restrict__ rowptr,
                                                    int* __restrict__ blk_sums) {
    __shared__ int sh[256];
    const int t = threadIdx.x;
    const int base = blockIdx.x * 512;
    const int i0 = base + 2 * t, i1 = i0 + 1;
    int d0 = 0, d1 = 0;
    if (i0 < N_NODES) {
        u32 v = degpack[i0 >> 1];
        d0 = (int)(v & 0xFFFFu);
        d1 = (int)(v >> 16);
    }
    const int pair = d0 + d1;
    int v = pair;
    sh[t] = v;
    __syncthreads();
#pragma unroll
    for (int off = 1; off < 256; off <<= 1) {
        int add = (t >= off) ? sh[t - off] : 0;
        __syncthreads();
        v += add;
        sh[t] = v;
        __syncthreads();
    }
    const int excl = v - pair;
    if (i0 < N_NODES) rowptr[i0] = excl;
    if (i1 < N_NODES) rowptr[i1] = excl + d0;
    if (t == 255) blk_sums[blockIdx.x] = v;
}

__global__ __launch_bounds__(128) void scan2_kernel(const int* __restrict__ blk_sums,
                                                    int* __restrict__ blk_offs,
                                                    int* __restrict__ rowptr) {
    __shared__ int sh[128];
    const int t = threadIdx.x;
    const int orig = (t < SCAN_NB) ? blk_sums[t] : 0;
    int v = orig;
    sh[t] = v;
    __syncthreads();
#pragma unroll
    for (int off = 1; off < 128; off <<= 1) {
        int add = (t >= off) ? sh[t - off] : 0;
        __syncthreads();
        v += add;
        sh[t] = v;
        __syncthreads();
    }
    if (t < SCAN_NB) blk_offs[t] = v - orig;
    if (t == 127) rowptr[N_NODES] = v;
}

__global__ void scan3_kernel(int* __restrict__ rowptr,
                             const int* __restrict__ blk_offs) {
    int i = blockIdx.x * blockDim.x + threadIdx.x;
    if (i >= N_NODES) return;
    rowptr[i] += blk_offs[i >> 9];
}

// ---------------------------------------------------------------------------
// CSR placement, SINGLE pass per chunk, no global atomics. 1024 threads,
// 100KB packed-u16 rank table: atomicAdd's RETURN VALUE is this edge's local
// rank within (chunk, node). Every lane active; dst16/edge_index/ew reads
// fully coalesced; zero redundant passes.
// slot = rowptr[d] + prefpack[c][d] + rank. Edge order within a row is
// nondeterministic (fp32 sum-order rounding only; absorbed by tolerance).
// ---------------------------------------------------------------------------
__global__ __launch_bounds__(1024) void place_kernel(const int* __restrict__ edge_index,
                                                     const float* __restrict__ ew,
                                                     const u16* __restrict__ dst16,
                                                     const int* __restrict__ rowptr,
                                                     const u32* __restrict__ prefpack,
                                                     int2* __restrict__ csr) {
    __shared__ u32 lrank[HWORDS2];
    const int c = blockIdx.x;
    const int t = threadIdx.x;
    for (int i = t; i < HWORDS2; i += 1024) lrank[i] = 0;
    __syncthreads();
    const int base = c * EDGES_PER_CHUNK;
    for (int i = t; i < EDGES_PER_CHUNK; i += 1024) {
        const int e = base + i;
        const int d = (int)dst16[e];
        const int sh = (d & 1) * 16;
        const u32 old = atomicAdd(&lrank[d >> 1], 1u << sh);
        const int lpos = (int)((old >> sh) & 0xFFFFu);
        const u32 pw = prefpack[(size_t)c * HWORDS2 + (d >> 1)];
        const int pref = (int)((pw >> sh) & 0xFFFFu);
        int2 ent;
        ent.x = edge_index[e];
        ent.y = __float_as_int(ew[e]);
        csr[rowptr[d] + pref + lpos] = ent;
    }
}

// ---------------------------------------------------------------------------
// FUSED gather + GEMM, layer 0. Block = 1024 threads (16 waves) owns 64 nodes.
// ---------------------------------------------------------------------------
__global__ __launch_bounds__(1024) void fused_l0(
    const u16* __restrict__ xb, const int* __restrict__ rowptr,
    const int2* __restrict__ csr, const u16* __restrict__ Bp0,
    const float* __restrict__ bias1, const float* __restrict__ bias3,
    float* __restrict__ cvec, u16* __restrict__ h1out) {
    __shared__ u16 A[64][200];
    __shared__ float csh[64];
    const int tid = threadIdx.x;
    const int wv = tid >> 6;
    const int lane = tid & 63;
    const int node_base = blockIdx.x * 64;
    const uint4* x4 = (const uint4*)xb;
    const int cg = lane & 7;
    const int eg = lane >> 3;

    // ---- phase A: gather 4 nodes per wave
    for (int k = 0; k < 4; k++) {
        const int row = wv * 4 + k;
        const int node = node_base + row;
        float sv[8];
#pragma unroll
        for (int j = 0; j < 8; j++) sv[j] = 0.f;
        float wsum = 0.f;
        if (node < N_NODES)
            gather_rows8(csr, x4, rowptr[node], rowptr[node + 1], eg, cg, sv, wsum);
#pragma unroll
        for (int off = 32; off >= 8; off >>= 1) {
#pragma unroll
            for (int j = 0; j < 8; j++) sv[j] += __shfl_xor(sv[j], off);
            wsum += __shfl_xor(wsum, off);
        }
        if (lane < 8) {
            const float cn = wsum;
            uint4 hv = {0u, 0u, 0u, 0u};
            if (node < N_NODES) hv = x4[(size_t)node * 8 + cg];
            uint4 so;
            so.x = packbf(sv[0], sv[1]);
            so.y = packbf(sv[2], sv[3]);
            so.z = packbf(sv[4], sv[5]);
            so.w = packbf(sv[6], sv[7]);
            *(uint4*)&A[row][cg * 8] = hv;
            *(uint4*)&A[row][64 + cg * 8] = so;
            float h0, h1f;
            uint4 co;
            bfpair(hv.x, h0, h1f); co.x = packbf(cn * h0, cn * h1f);
            bfpair(hv.y, h0, h1f); co.y = packbf(cn * h0, cn * h1f);
            bfpair(hv.z, h0, h1f); co.z = packbf(cn * h0, cn * h1f);
            bfpair(hv.w, h0, h1f); co.w = packbf(cn * h0, cn * h1f);
            *(uint4*)&A[row][128 + cg * 8] = co;
            if (cg == 0) {
                csh[row] = cn;
                if (node < N_NODES) cvec[node] = cn;
            }
        }
    }
    __syncthreads();

    // ---- phase B: 64x64 GEMM, K=192
    const int l15 = lane & 15;
    const int q = lane >> 4;
    const int qo = q * 8;
    const int mt = wv >> 2, nt = wv & 3;
    f32x4 acc = {0.f, 0.f, 0.f, 0.f};
#pragma unroll
    for (int chunk = 0; chunk < 6; chunk++) {
        bf16x8 a = *(const bf16x8*)&A[mt * 16 + l15][chunk * 32 + qo];
        bf16x8 b = *(const bf16x8*)(Bp0 + (((size_t)(chunk * 4 + nt) * 64 + lane) << 3));
        acc = __builtin_amdgcn_mfma_f32_16x16x32_bf16(a, b, acc, 0, 0, 0);
    }
    const int col = nt * 16 + l15;
    const float B3 = bias3[col];
    const float B1 = bias1[col];
#pragma unroll
    for (int reg = 0; reg < 4; reg++) {
        const int lrow = mt * 16 + q * 4 + reg;
        const int row = node_base + lrow;
        if (row < N_NODES) {
            const float val = acc[reg] + B3 + csh[lrow] * B1;
            h1out[(size_t)row * 64 + col] = f2bf(elu_f(val));
        }
    }
}

// ---------------------------------------------------------------------------
// FUSED gather + GEMM1 + wide GEMM2, layer 1 (+ layer-2 pre-GEMM).
// Phase C writes z,u -> zu[N][128] and y -> yb[N][64].
// ---------------------------------------------------------------------------
__global__ __launch_bounds__(1024) void fused_l1(
    const u16* __restrict__ h1in, const int* __restrict__ rowptr,
    const int2* __restrict__ csr, const u16* __restrict__ Bp1,
    const u16* __restrict__ Bp2, const float* __restrict__ bias1,
    const float* __restrict__ bias3, u16* __restrict__ zu,
    u16* __restrict__ yb) {
    __shared__ u16 A[64][200];
    __shared__ u16 ht[64][136];
    __shared__ float csh[64];
    const int tid = threadIdx.x;
    const int wv = tid >> 6;
    const int lane = tid & 63;
    const int node_base = blockIdx.x * 64;
    const uint4* x4 = (const uint4*)h1in;
    const int cg = lane & 7;
    const int eg = lane >> 3;

    // ---- phase A
    for (int k = 0; k < 4; k++) {
        const int row = wv * 4 + k;
        const int node = node_base + row;
        float sv[8];
#pragma unroll
        for (int j = 0; j < 8; j++) sv[j] = 0.f;
        float wsum = 0.f;
        if (node < N_NODES)
            gather_rows8(csr, x4, rowptr[node], rowptr[node + 1], eg, cg, sv, wsum);
#pragma unroll
        for (int off = 32; off >= 8; off >>= 1) {
#pragma unroll
            for (int j = 0; j < 8; j++) sv[j] += __shfl_xor(sv[j], off);
            wsum += __shfl_xor(wsum, off);
        }
        if (lane < 8) {
            const float cn = wsum;
            uint4 hv = {0u, 0u, 0u, 0u};
            if (node < N_NODES) hv = x4[(size_t)node * 8 + cg];
            uint4 so;
            so.x = packbf(sv[0], sv[1]);
            so.y = packbf(sv[2], sv[3]);
            so.z = packbf(sv[4], sv[5]);
            so.w = packbf(sv[6], sv[7]);
            *(uint4*)&A[row][cg * 8] = hv;
            *(uint4*)&A[row][64 + cg * 8] = so;
            float h0, h1f;
            uint4 co;
            bfpair(hv.x, h0, h1f); co.x = packbf(cn * h0, cn * h1f);
            bfpair(hv.y, h0, h1f); co.y = packbf(cn * h0, cn * h1f);
            bfpair(hv.z, h0, h1f); co.z = packbf(cn * h0, cn * h1f);
            bfpair(hv.w, h0, h1f); co.w = packbf(cn * h0, cn * h1f);
            *(uint4*)&A[row][128 + cg * 8] = co;
            if (cg == 0) csh[row] = cn;
        }
    }
    __syncthreads();

    const int l15 = lane & 15;
    const int q = lane >> 4;
    const int qo = q * 8;

    // ---- phase B: 64x128 GEMM, K=192, epilogue to LDS ht
    {
        const int mt = wv >> 2;
        const int nt0 = (wv & 3) * 2;
        f32x4 acc0 = {0.f, 0.f, 0.f, 0.f};
        f32x4 acc1 = {0.f, 0.f, 0.f, 0.f};
#pragma unroll
        for (int chunk = 0; chunk < 6; chunk++) {
            bf16x8 a = *(const bf16x8*)&A[mt * 16 + l15][chunk * 32 + qo];
            bf16x8 bf0 = *(const bf16x8*)(Bp1 + (((size_t)(chunk * 8 + nt0) * 64 + lane) << 3));
            bf16x8 bf1 = *(const bf16x8*)(Bp1 + (((size_t)(chunk * 8 + nt0 + 1) * 64 + lane) << 3));
            acc0 = __builtin_amdgcn_mfma_f32_16x16x32_bf16(a, bf0, acc0, 0, 0, 0);
            acc1 = __builtin_amdgcn_mfma_f32_16x16x32_bf16(a, bf1, acc1, 0, 0, 0);
        }
#pragma unroll
        for (int ni = 0; ni < 2; ni++) {
            const int col = (nt0 + ni) * 16 + l15;
            const float B3 = bias3[col];
            const float B1 = bias1[col];
            const f32x4 av = ni ? acc1 : acc0;
#pragma unroll
            for (int reg = 0; reg < 4; reg++) {
                const int lrow = mt * 16 + q * 4 + reg;
                ht[lrow][col] = f2bf(elu_f(av[reg] + B3 + csh[lrow] * B1));
            }
        }
    }
    __syncthreads();

    // ---- phase C: 64x192 GEMM, K=128 from ht; split output zu / yb
    {
        const int mt = wv >> 2;
        const int ntb = (wv & 3) * 3;
        f32x4 acc[3] = {};
#pragma unroll
        for (int chunk = 0; chunk < 4; chunk++) {
            bf16x8 a = *(const bf16x8*)&ht[mt * 16 + l15][chunk * 32 + qo];
#pragma unroll
            for (int j = 0; j < 3; j++) {
                bf16x8 b = *(const bf16x8*)(Bp2 + (((size_t)(chunk * 12 + ntb + j) * 64 + lane) << 3));
                acc[j] = __builtin_amdgcn_mfma_f32_16x16x32_bf16(a, b, acc[j], 0, 0, 0);
            }
        }
#pragma unroll
        for (int j = 0; j < 3; j++) {
            const int col = (ntb + j) * 16 + l15;
#pragma unroll
            for (int reg = 0; reg < 4; reg++) {
                const int row = node_base + mt * 16 + q * 4 + reg;
                if (row < N_NODES) {
                    const u16 v = f2bf(acc[j][reg]);
                    if (col < 128) zu[(size_t)row * 128 + col] = v;
                    else           yb[(size_t)row * 64 + (col - 128)] = v;
                }
            }
        }
    }
}

// ---------------------------------------------------------------------------
// Layer-2 gather + fused epilogue. Random reads from yb[N][64] (6.4MB hot
// set, 8 uint4/row); z,u streamed from zu[N][128].
// h3[i] = elu( z_i + c_i*u_i + sum_e w_e * y[src_e] + b3 + c_i*b1 )
// ---------------------------------------------------------------------------
__global__ __launch_bounds__(256) void gather2_kernel(
    const u16* __restrict__ zu, const u16* __restrict__ yb,
    const int* __restrict__ rowptr, const int2* __restrict__ csr,
    const float* __restrict__ c, const float* __restrict__ bias1,
    const float* __restrict__ bias3, u16* __restrict__ h3) {
    const int gid = blockIdx.x * 256 + threadIdx.x;
    const int node = gid >> 6;
    if (node >= N_NODES) return;
    const int lane = threadIdx.x & 63;
    const int cg = lane & 7;
    const int eg = lane >> 3;

    float sv[8];
#pragma unroll
    for (int j = 0; j < 8; j++) sv[j] = 0.f;
    float wdummy = 0.f;
    gather_rows8(csr, (const uint4*)yb, rowptr[node], rowptr[node + 1], eg, cg,
                 sv, wdummy);

#pragma unroll
    for (int off = 32; off >= 8; off >>= 1) {
#pragma unroll
        for (int j = 0; j < 8; j++) sv[j] += __shfl_xor(sv[j], off);
    }

    if (lane < 8) {
        const float cn = c[node];
        const u16* zr = zu + (size_t)node * 128;
        uint4 zv = ((const uint4*)zr)[cg];        // z cols cg*8..cg*8+7
        uint4 uv = ((const uint4*)(zr + 64))[cg]; // u cols cg*8..cg*8+7
        float z0, z1, z2, z3, z4, z5, z6, z7;
        float u0, u1, u2, u3, u4, u5, u6, u7;
        bfpair(zv.x, z0, z1); bfpair(zv.y, z2, z3);
        bfpair(zv.z, z4, z5); bfpair(zv.w, z6, z7);
        bfpair(uv.x, u0, u1); bfpair(uv.y, u2, u3);
        bfpair(uv.z, u4, u5); bfpair(uv.w, u6, u7);
        const float4 b3a = *(const float4*)(bias3 + cg * 8);
        const float4 b3b = *(const float4*)(bias3 + cg * 8 + 4);
        const float4 b1a = *(const float4*)(bias1 + cg * 8);
        const float4 b1b = *(const float4*)(bias1 + cg * 8 + 4);
        float o0 = elu_f(z0 + cn * u0 + sv[0] + b3a.x + cn * b1a.x);
        float o1 = elu_f(z1 + cn * u1 + sv[1] + b3a.y + cn * b1a.y);
        float o2 = elu_f(z2 + cn * u2 + sv[2] + b3a.z + cn * b1a.z);
        float o3 = elu_f(z3 + cn * u3 + sv[3] + b3a.w + cn * b1a.w);
        float o4 = elu_f(z4 + cn * u4 + sv[4] + b3b.x + cn * b1b.x);
        float o5 = elu_f(z5 + cn * u5 + sv[5] + b3b.y + cn * b1b.y);
        float o6 = elu_f(z6 + cn * u6 + sv[6] + b3b.z + cn * b1b.z);
        float o7 = elu_f(z7 + cn * u7 + sv[7] + b3b.w + cn * b1b.w);
        uint4 ov;
        ov.x = packbf(o0, o1);
        ov.y = packbf(o2, o3);
        ov.z = packbf(o4, o5);
        ov.w = packbf(o6, o7);
        ((uint4*)h3)[(size_t)node * 8 + cg] = ov;
    }
}

// ---------------------------------------------------------------------------
// out[g, :] = max over nodes of graph g of h[:, :64] (bf16 in, fp32 out)
// ---------------------------------------------------------------------------
__global__ void pool_kernel(const u16* __restrict__ h,
                            const int* __restrict__ batch,
                            float* __restrict__ out) {
    const int g = blockIdx.x;
    const int tid = threadIdx.x;
    int lo = 0, hi = N_NODES;
    while (lo < hi) { int mid = (lo + hi) >> 1; if (batch[mid] < g) lo = mid + 1; else hi = mid; }
    const int beg = lo;
    lo = beg; hi = N_NODES;
    while (lo < hi) { int mid = (lo + hi) >> 1; if (batch[mid] < g + 1) lo = mid + 1; else hi = mid; }
    const int end = lo;

    __shared__ float red[256];
    const int col = tid & 63;
    const int rg = tid >> 6;
    float m = -3.0e38f;
    for (int r = beg + rg; r < end; r += 4) m = fmaxf(m, bf2f(h[(size_t)r * 64 + col]));
    red[tid] = m;
    __syncthreads();
    if (tid < 64) {
        m = fmaxf(fmaxf(red[tid], red[tid + 64]), fmaxf(red[tid + 128], red[tid + 192]));
        out[g * 64 + tid] = m;
    }
}

extern "C" void kernel_launch(void* const* d_in, const int* in_sizes, int n_in,
                              void* d_out, int out_size, void* d_ws, size_t ws_size,
                              hipStream_t stream) {
    const float* x = (const float*)d_in[0];
    const int* ei = (const int*)d_in[1];
    const float* ea = (const float*)d_in[2];
    const int* batch = (const int*)d_in[3];
    const float* wfc = (const float*)d_in[4];
    const float* bfc = (const float*)d_in[5];
    const float* w1_0 = (const float*)d_in[6];
    const float* b1_0 = (const float*)d_in[7];
    const float* w2_0 = (const float*)d_in[8];
    const float* w3_0 = (const float*)d_in[9];
    const float* b3_0 = (const float*)d_in[10];
    const float* w1_1 = (const float*)d_in[11];
    const float* b1_1 = (const float*)d_in[12];
    const float* w2_1 = (const float*)d_in[13];
    const float* w3_1 = (const float*)d_in[14];
    const float* b3_1 = (const float*)d_in[15];
    const float* w1_2 = (const float*)d_in[16];
    const float* b1_2 = (const float*)d_in[17];
    const float* w2_2 = (const float*)d_in[18];
    const float* w3_2 = (const float*)d_in[19];
    const float* b3_2 = (const float*)d_in[20];
    float* out = (float*)d_out;

    char* ws = (char*)d_ws;
    float* ew      = (float*)(ws);                 // E f32      3.2 MB
    float* c       = (float*)(ws + 3200000);       // N f32
    int*   rowptr  = (int*)  (ws + 3800000);       // N+1 int
    int2*  csr     = (int2*) (ws + 4000128);       // E int2     6.4 MB
    u16*   xb      = (u16*)  (ws + 10400128);      // N*64 bf16  6.4 MB
    u32*   partial = (u32*)  (ws + 16800128);      // 128*25000 u32 = 12.8 MB
    u16*   dst16   = (u16*)  (ws + 29600128);      // E u16      1.6 MB
    u32*   degpack = (u32*)  (ws + 31600128);      // 100 KB
    u16*   h1      = (u16*)  (ws + 42400128);      // N*64 bf16  6.4 MB
    u16*   zu      = (u16*)  (ws + 48800128);      // N*128 bf16 12.8 MB
    u16*   yb      = (u16*)  (ws + 61600128);      // N*64 bf16  6.4 MB
    u16*   bp0     = (u16*)  (ws + 68000128);      // 24 KB packed weights L0
    u16*   bp1     = (u16*)  (ws + 68024704);      // 48 KB L1
    u16*   bp2     = (u16*)  (ws + 68073856);      // 48 KB L2 wide
    int* blk_sums  = (int*)  (ws + 68123008);
    int* blk_offs  = (int*)  (ws + 68123520);
    // aliases into regions dead at time of use:
    u32* prefpack = (u32*)zu;   // 12.8 MB, dead before fused_l1 writes zu
    u16* h3 = xb;               // N*64 bf16 (xb dead after fused_l0)

    // fused prep: ew + conv_x + pack_w in one launch
    prep_kernel<<<6280, 256, 0, stream>>>(ea, wfc, bfc, ei, ew, dst16, x, xb,
                                          w3_0, w1_0, w2_0, w3_1, w1_1, w2_1,
                                          w3_2, w1_2, w2_2, bp0, bp1, bp2);
    // --- CSR build: single-pass hist + chunk scan + single-pass ranked place
    deg_hist_kernel<<<HCHUNKS, 1024, 0, stream>>>(dst16, partial);
    scan_chunks_kernel<<<TS_B, 256, 0, stream>>>(partial, prefpack, degpack);
    scan1_kernel<<<SCAN_NB, 256, 0, stream>>>(degpack, rowptr, blk_sums);
    scan2_kernel<<<1, 128, 0, stream>>>(blk_sums, blk_offs, rowptr);
    scan3_kernel<<<(N_NODES + 255) / 256, 256, 0, stream>>>(rowptr, blk_offs);
    place_kernel<<<HCHUNKS, 1024, 0, stream>>>(ei, ew, dst16, rowptr, prefpack, csr);

    const int RB = (N_NODES + 63) / 64;           // 782 row-blocks
    const int GBLK = (N_NODES * 64 + 255) / 256;  // one wave per node

    // layer 0: fused gather + GEMM
    fused_l0<<<RB, 1024, 0, stream>>>(xb, rowptr, csr, bp0, b1_0, b3_0, c, h1);

    // layer 1 + layer-2 wide GEMM: fused gather + GEMM1 + GEMM2
    fused_l1<<<RB, 1024, 0, stream>>>(h1, rowptr, csr, bp1, bp2, b1_1, b3_1, zu, yb);

    // layer 2 gather in output space + fused epilogue
    gather2_kernel<<<GBLK, 256, 0, stream>>>(zu, yb, rowptr, csr, c, b1_2, b3_2, h3);

    // global max pool
    pool_kernel<<<NUM_GRAPHS_, 256, 0, stream>>>(h3, batch, out);
}

// Round 13
// 322.061 us; speedup vs baseline: 1.0385x; 1.0385x over previous
//
#include <hip/hip_runtime.h>
#include <math.h>

#define N_NODES 50000
#define N_EDGES 800000
#define NUM_GRAPHS_ 128
#define SCAN_NB 98   // ceil(50000/512)
#define NPASS 4
#define NODES_PER_PASS 12500 // 50000/4
#define HCHUNKS 128
#define EDGES_PER_CHUNK 6250 // 800000/128
#define HWORDS 12500         // 25000 nodes per half, 2 per word
#define TS_BPH 196           // transpose-scan blocks per half: ceil(12500/64)

typedef unsigned short u16;
typedef unsigned int u32;
typedef __attribute__((ext_vector_type(8))) short bf16x8;   // 8 bf16 (4 VGPRs)
typedef __attribute__((ext_vector_type(4))) float f32x4;    // 4 fp32

__device__ __forceinline__ float elu_f(float v) {
    return v > 0.f ? v : (__expf(v) - 1.f);
}
__device__ __forceinline__ u16 f2bf(float f) {  // RNE
    u32 u = __float_as_uint(f);
    u += 0x7FFFu + ((u >> 16) & 1u);
    return (u16)(u >> 16);
}
__device__ __forceinline__ float bf2f(u16 h) {
    return __uint_as_float(((u32)h) << 16);
}
__device__ __forceinline__ void bfpair(u32 v, float& lo, float& hi) {
    lo = __uint_as_float(v << 16);
    hi = __uint_as_float(v & 0xFFFF0000u);
}
__device__ __forceinline__ u32 packbf(float lo, float hi) {
    return (u32)f2bf(lo) | ((u32)f2bf(hi) << 16);
}

// ---------------------------------------------------------------------------
// Fused prep: blocks [0,3125) edge weights + dst16; [3125,6250) x->bf16;
// [6250,6280) weight packing.
// ---------------------------------------------------------------------------
__global__ void prep_kernel(const float* __restrict__ edge_attr,
                            const float* __restrict__ w_fc1,
                            const float* __restrict__ b_fc1,
                            const int* __restrict__ edge_index,
                            float* __restrict__ ew,
                            u16* __restrict__ dst16,
                            const float* __restrict__ x, u16* __restrict__ xb,
                            const float* __restrict__ w3_0, const float* __restrict__ w1_0, const float* __restrict__ w2_0,
                            const float* __restrict__ w3_1, const float* __restrict__ w1_1, const float* __restrict__ w2_1,
                            const float* __restrict__ w3_2, const float* __restrict__ w1_2, const float* __restrict__ w2_2,
                            u16* __restrict__ bp0, u16* __restrict__ bp1, u16* __restrict__ bp2) {
    const int b = blockIdx.x;
    if (b < 3125) {
        const int e = b * 256 + threadIdx.x;
        const float4* ea = (const float4*)(edge_attr + (size_t)e * 16);
        const float4* wf = (const float4*)w_fc1;
        float acc = b_fc1[0];
#pragma unroll
        for (int i = 0; i < 4; i++) {
            float4 a = ea[i], w = wf[i];
            acc += a.x * w.x + a.y * w.y + a.z * w.z + a.w * w.w;
        }
        ew[e] = acc;
        dst16[e] = (u16)edge_index[N_EDGES + e];
    } else if (b < 6250) {
        const int g = (b - 3125) * 256 + threadIdx.x;
        float4 v = ((const float4*)x)[g];
        uint2 o;
        o.x = packbf(v.x, v.y);
        o.y = packbf(v.z, v.w);
        ((uint2*)xb)[g] = o;
    } else {
        const int t = (b - 6250) * 256 + threadIdx.x;
        u16 buf[8];
        if (t < 4608) {
            int DOUT, lid;
            const float *w3, *w1, *w2;
            u16* bp;
            if (t < 1536) { DOUT = 64;  lid = t;        w3 = w3_0; w1 = w1_0; w2 = w2_0; bp = bp0; }
            else          { DOUT = 128; lid = t - 1536; w3 = w3_1; w1 = w1_1; w2 = w2_1; bp = bp1; }
            const int NT = DOUT / 16;
            const int lane = lid & 63;
            const int fragid = lid >> 6;
            const int chunk = fragid / NT;
            const int ntile = fragid % NT;
            const int n = ntile * 16 + (lane & 15);
            const int kbase = chunk * 32 + (lane >> 4) * 8;
#pragma unroll
            for (int j = 0; j < 8; j++) {
                int k = kbase + j;
                int region = k / 64;
                int kk = k - region * 64;
                float v = (region == 0) ? w3[kk * DOUT + n]
                        : (region == 1) ? w1[kk * DOUT + n]
                                        : -w2[kk * DOUT + n];
                buf[j] = f2bf(v);
            }
            *(bf16x8*)(bp + ((size_t)lid << 3)) = *(bf16x8*)buf;
        } else if (t < 7680) {
            const int lid = t - 4608;          // 0..3071
            const int NT = 12;
            const int lane = lid & 63;
            const int fragid = lid >> 6;       // 0..47
            const int chunk = fragid / NT;     // 0..3
            const int ntile = fragid % NT;     // 0..11
            const int n = ntile * 16 + (lane & 15);   // 0..191
            const int kbase = chunk * 32 + (lane >> 4) * 8;  // 0..127
#pragma unroll
            for (int j = 0; j < 8; j++) {
                int k = kbase + j;
                float v = (n < 64)  ? w3_2[k * 64 + n]
                        : (n < 128) ? -w2_2[k * 64 + (n - 64)]
                                    : w1_2[k * 64 + (n - 128)];
                buf[j] = f2bf(v);
            }
            *(bf16x8*)(bp2 + ((size_t)lid << 3)) = *(bf16x8*)buf;
        }
    }
}

// ---------------------------------------------------------------------------
// Degree histogram per (chunk, half): LDS atomics only, dense write.
// ---------------------------------------------------------------------------
__global__ __launch_bounds__(256) void deg_hist_kernel(const u16* __restrict__ dst16,
                                                       u32* __restrict__ partial) {
    __shared__ u32 bins[HWORDS];
    const int c = blockIdx.x >> 1;
    const int p = blockIdx.x & 1;
    const int t = threadIdx.x;
    for (int i = t; i < HWORDS; i += 256) bins[i] = 0;
    __syncthreads();
    const int base = c * EDGES_PER_CHUNK;
    const int nlo = p * 25000;
    for (int i = t; i < EDGES_PER_CHUNK; i += 256) {
        const int b = (int)dst16[base + i] - nlo;
        if ((unsigned)b < 25000u)
            atomicAdd(&bins[b >> 1], 1u << ((b & 1) * 16));
    }
    __syncthreads();
    u32* outp = partial + (size_t)blockIdx.x * HWORDS;
    for (int i = t; i < HWORDS; i += 256) outp[i] = bins[i];
}

// ---------------------------------------------------------------------------
// Exclusive scan along the chunk axis, register-parallel (32 chunks/thread).
// ---------------------------------------------------------------------------
__global__ __launch_bounds__(256) void scan_chunks_kernel(const u32* __restrict__ partial,
                                                          u32* __restrict__ prefpack,
                                                          u32* __restrict__ degpack) {
    __shared__ u32 qsums[4][64];
    const int t = threadIdx.x;
    const int p = (blockIdx.x >= TS_BPH) ? 1 : 0;
    const int wh0 = (blockIdx.x - p * TS_BPH) << 6;
    const int wl = t & 63;
    const int cq = t >> 6;           // quarter: chunks [cq*32, cq*32+32)
    const int wh = wh0 + wl;
    const bool ok = wh < HWORDS;

    u32 vals[32];
#pragma unroll
    for (int i = 0; i < 32; i++) {
        const int c = cq * 32 + i;
        vals[i] = ok ? partial[(size_t)((c << 1) + p) * HWORDS + wh] : 0u;
    }
    u32 s = 0;
#pragma unroll
    for (int i = 0; i < 32; i++) s += vals[i];
    qsums[cq][wl] = s;
    __syncthreads();
    u32 run = 0;
#pragma unroll
    for (int j = 0; j < 4; j++)
        if (j < cq) run += qsums[j][wl];

    if (ok) {
        const int g = p * HWORDS + wh;
#pragma unroll
        for (int i = 0; i < 32; i++) {
            const int c = cq * 32 + i;
            prefpack[(size_t)c * 25000 + g] = run;
            run += vals[i];
        }
        if (cq == 3) degpack[g] = run;
    }
}

// ---------------------------------------------------------------------------
// Hierarchical exclusive scan of degpack -> rowptr[N+1]
// ---------------------------------------------------------------------------
__global__ __launch_bounds__(256) void scan1_kernel(const u32* __restrict__ degpack,
                                                    int* __restrict__ rowptr,
                                                    int* __restrict__ blk_sums) {
    __shared__ int sh[256];
    const int t = threadIdx.x;
    const int base = blockIdx.x * 512;
    const int i0 = base + 2 * t, i1 = i0 + 1;
    int d0 = 0, d1 = 0;
    if (i0 < N_NODES) {
        u32 v = degpack[i0 >> 1];
        d0 = (int)(v & 0xFFFFu);
        d1 = (int)(v >> 16);
    }
    const int pair = d0 + d1;
    int v = pair;
    sh[t] = v;
    __syncthreads();
#pragma unroll
    for (int off = 1; off < 256; off <<= 1) {
        int add = (t >= off) ? sh[t - off] : 0;
        __syncthreads();
        v += add;
        sh[t] = v;
        __syncthreads();
    }
    const int excl = v - pair;
    if (i0 < N_NODES) rowptr[i0] = excl;
    if (i1 < N_NODES) rowptr[i1] = excl + d0;
    if (t == 255) blk_sums[blockIdx.x] = v;
}

__global__ __launch_bounds__(128) void scan2_kernel(const int* __restrict__ blk_sums,
                                                    int* __restrict__ blk_offs,
                                                    int* __restrict__ rowptr) {
    __shared__ int sh[128];
    const int t = threadIdx.x;
    const int orig = (t < SCAN_NB) ? blk_sums[t] : 0;
    int v = orig;
    sh[t] = v;
    __syncthreads();
#pragma unroll
    for (int off = 1; off < 128; off <<= 1) {
        int add = (t >= off) ? sh[t - off] : 0;
        __syncthreads();
        v += add;
        sh[t] = v;
        __syncthreads();
    }
    if (t < SCAN_NB) blk_offs[t] = v - orig;
    if (t == 127) rowptr[N_NODES] = v;
}

__global__ void scan3_kernel(int* __restrict__ rowptr,
                             const int* __restrict__ blk_offs) {
    int i = blockIdx.x * blockDim.x + threadIdx.x;
    if (i >= N_NODES) return;
    rowptr[i] += blk_offs[i >> 9];
}

// ---------------------------------------------------------------------------
// CSR placement, NO global atomics (counting sort). NPASS=4 (50KB lcur).
// ---------------------------------------------------------------------------
__global__ __launch_bounds__(256) void place_kernel(const int* __restrict__ edge_index,
                                                    const float* __restrict__ ew,
                                                    const u16* __restrict__ dst16,
                                                    const int* __restrict__ rowptr,
                                                    const u32* __restrict__ prefpack,
                                                    int2* __restrict__ csr) {
    __shared__ int lcur[NODES_PER_PASS];
    const int pass = blockIdx.x & (NPASS - 1);
    const int c = blockIdx.x >> 2;
    const int lo = pass * NODES_PER_PASS;
    const int t = threadIdx.x;
    for (int i = t; i < NODES_PER_PASS; i += 256) lcur[i] = 0;
    __syncthreads();
    const int base = c * EDGES_PER_CHUNK;
    for (int i = t; i < EDGES_PER_CHUNK; i += 256) {
        const int e = base + i;
        const int d = (int)dst16[e];
        const int dl = d - lo;
        if ((unsigned)dl < (unsigned)NODES_PER_PASS) {
            u32 pw = prefpack[(size_t)c * 25000 + (d >> 1)];
            int pref = (int)((pw >> ((d & 1) * 16)) & 0xFFFFu);
            int lpos = atomicAdd(&lcur[dl], 1);
            int2 ent;
            ent.x = edge_index[e];
            ent.y = __float_as_int(ew[e]);
            csr[rowptr[d] + pref + lpos] = ent;
        }
    }
}

// ---------------------------------------------------------------------------
// FUSED gather + GEMM, layer 0. Block = 1024 threads (16 waves) owns 64 nodes.
// Gather: 16 lanes/row uint2, 4 edge-groups, 2-deep (round-7 proven form).
// ---------------------------------------------------------------------------
__global__ __launch_bounds__(1024) void fused_l0(
    const u16* __restrict__ xb, const int* __restrict__ rowptr,
    const int2* __restrict__ csr, const u16* __restrict__ Bp0,
    const float* __restrict__ bias1, const float* __restrict__ bias3,
    float* __restrict__ cvec, u16* __restrict__ h1out) {
    __shared__ u16 A[64][200];
    __shared__ float csh[64];
    const int tid = threadIdx.x;
    const int wv = tid >> 6;
    const int lane = tid & 63;
    const int node_base = blockIdx.x * 64;
    const uint2* x2 = (const uint2*)xb;
    const int cg = lane & 15;
    const int eg = lane >> 4;

    // ---- phase A: gather 4 nodes per wave
    for (int k = 0; k < 4; k++) {
        const int row = wv * 4 + k;
        const int node = node_base + row;
        float a0 = 0.f, a1 = 0.f, a2 = 0.f, a3 = 0.f;
        float b0 = 0.f, b1 = 0.f, b2 = 0.f, b3 = 0.f;
        float wsum = 0.f;
        if (node < N_NODES) {
            const int beg = rowptr[node];
            const int end = rowptr[node + 1];
            int p = beg + eg;
            for (; p + 4 < end; p += 8) {
                int2 e0 = csr[p];
                int2 e1 = csr[p + 4];
                float w0 = __int_as_float(e0.y);
                float w1 = __int_as_float(e1.y);
                uint2 v0 = x2[(size_t)e0.x * 16 + cg];
                uint2 v1 = x2[(size_t)e1.x * 16 + cg];
                float f0, f1, f2, f3, g0, g1, g2, g3;
                bfpair(v0.x, f0, f1); bfpair(v0.y, f2, f3);
                bfpair(v1.x, g0, g1); bfpair(v1.y, g2, g3);
                a0 += w0 * f0; a1 += w0 * f1; a2 += w0 * f2; a3 += w0 * f3;
                b0 += w1 * g0; b1 += w1 * g1; b2 += w1 * g2; b3 += w1 * g3;
                wsum += w0 + w1;
            }
            if (p < end) {
                int2 e0 = csr[p];
                float w0 = __int_as_float(e0.y);
                uint2 v0 = x2[(size_t)e0.x * 16 + cg];
                float f0, f1, f2, f3;
                bfpair(v0.x, f0, f1); bfpair(v0.y, f2, f3);
                a0 += w0 * f0; a1 += w0 * f1; a2 += w0 * f2; a3 += w0 * f3;
                wsum += w0;
            }
        }
        a0 += b0; a1 += b1; a2 += b2; a3 += b3;
#pragma unroll
        for (int off = 32; off >= 16; off >>= 1) {
            a0 += __shfl_xor(a0, off);
            a1 += __shfl_xor(a1, off);
            a2 += __shfl_xor(a2, off);
            a3 += __shfl_xor(a3, off);
            wsum += __shfl_xor(wsum, off);
        }
        if (lane < 16) {
            const float cn = wsum;
            uint2 hv = (node < N_NODES) ? x2[(size_t)node * 16 + cg] : (uint2){0u, 0u};
            uint2 so;
            so.x = packbf(a0, a1);
            so.y = packbf(a2, a3);
            *(uint2*)&A[row][cg * 4] = hv;
            *(uint2*)&A[row][64 + cg * 4] = so;
            float h0, h1f, h2f, h3f;
            bfpair(hv.x, h0, h1f); bfpair(hv.y, h2f, h3f);
            uint2 co;
            co.x = packbf(cn * h0, cn * h1f);
            co.y = packbf(cn * h2f, cn * h3f);
            *(uint2*)&A[row][128 + cg * 4] = co;
            if (cg == 0) {
                csh[row] = cn;
                if (node < N_NODES) cvec[node] = cn;
            }
        }
    }
    __syncthreads();

    // ---- phase B: 64x64 GEMM, K=192
    const int l15 = lane & 15;
    const int q = lane >> 4;
    const int qo = q * 8;
    const int mt = wv >> 2, nt = wv & 3;
    f32x4 acc = {0.f, 0.f, 0.f, 0.f};
#pragma unroll
    for (int chunk = 0; chunk < 6; chunk++) {
        bf16x8 a = *(const bf16x8*)&A[mt * 16 + l15][chunk * 32 + qo];
        bf16x8 b = *(const bf16x8*)(Bp0 + (((size_t)(chunk * 4 + nt) * 64 + lane) << 3));
        acc = __builtin_amdgcn_mfma_f32_16x16x32_bf16(a, b, acc, 0, 0, 0);
    }
    const int col = nt * 16 + l15;
    const float B3 = bias3[col];
    const float B1 = bias1[col];
#pragma unroll
    for (int reg = 0; reg < 4; reg++) {
        const int lrow = mt * 16 + q * 4 + reg;
        const int row = node_base + lrow;
        if (row < N_NODES) {
            const float val = acc[reg] + B3 + csh[lrow] * B1;
            h1out[(size_t)row * 64 + col] = f2bf(elu_f(val));
        }
    }
}

// ---------------------------------------------------------------------------
// FUSED gather + GEMM1 + wide GEMM2, layer 1 (+ layer-2 pre-GEMM).
// Phase C writes z,u -> zu[N][128] and y -> yb[N][64] (separate buffers so
// gather2's random reads have a 6.4MB hot set instead of 19.2MB).
// ---------------------------------------------------------------------------
__global__ __launch_bounds__(1024) void fused_l1(
    const u16* __restrict__ h1in, const int* __restrict__ rowptr,
    const int2* __restrict__ csr, const u16* __restrict__ Bp1,
    const u16* __restrict__ Bp2, const float* __restrict__ bias1,
    const float* __restrict__ bias3, u16* __restrict__ zu,
    u16* __restrict__ yb) {
    __shared__ u16 A[64][200];
    __shared__ u16 ht[64][136];
    __shared__ float csh[64];
    const int tid = threadIdx.x;
    const int wv = tid >> 6;
    const int lane = tid & 63;
    const int node_base = blockIdx.x * 64;
    const uint2* x2 = (const uint2*)h1in;
    const int cg = lane & 15;
    const int eg = lane >> 4;

    // ---- phase A
    for (int k = 0; k < 4; k++) {
        const int row = wv * 4 + k;
        const int node = node_base + row;
        float a0 = 0.f, a1 = 0.f, a2 = 0.f, a3 = 0.f;
        float b0 = 0.f, b1 = 0.f, b2 = 0.f, b3 = 0.f;
        float wsum = 0.f;
        if (node < N_NODES) {
            const int beg = rowptr[node];
            const int end = rowptr[node + 1];
            int p = beg + eg;
            for (; p + 4 < end; p += 8) {
                int2 e0 = csr[p];
                int2 e1 = csr[p + 4];
                float w0 = __int_as_float(e0.y);
                float w1 = __int_as_float(e1.y);
                uint2 v0 = x2[(size_t)e0.x * 16 + cg];
                uint2 v1 = x2[(size_t)e1.x * 16 + cg];
                float f0, f1, f2, f3, g0, g1, g2, g3;
                bfpair(v0.x, f0, f1); bfpair(v0.y, f2, f3);
                bfpair(v1.x, g0, g1); bfpair(v1.y, g2, g3);
                a0 += w0 * f0; a1 += w0 * f1; a2 += w0 * f2; a3 += w0 * f3;
                b0 += w1 * g0; b1 += w1 * g1; b2 += w1 * g2; b3 += w1 * g3;
                wsum += w0 + w1;
            }
            if (p < end) {
                int2 e0 = csr[p];
                float w0 = __int_as_float(e0.y);
                uint2 v0 = x2[(size_t)e0.x * 16 + cg];
                float f0, f1, f2, f3;
                bfpair(v0.x, f0, f1); bfpair(v0.y, f2, f3);
                a0 += w0 * f0; a1 += w0 * f1; a2 += w0 * f2; a3 += w0 * f3;
                wsum += w0;
            }
        }
        a0 += b0; a1 += b1; a2 += b2; a3 += b3;
#pragma unroll
        for (int off = 32; off >= 16; off >>= 1) {
            a0 += __shfl_xor(a0, off);
            a1 += __shfl_xor(a1, off);
            a2 += __shfl_xor(a2, off);
            a3 += __shfl_xor(a3, off);
            wsum += __shfl_xor(wsum, off);
        }
        if (lane < 16) {
            const float cn = wsum;
            uint2 hv = (node < N_NODES) ? x2[(size_t)node * 16 + cg] : (uint2){0u, 0u};
            uint2 so;
            so.x = packbf(a0, a1);
            so.y = packbf(a2, a3);
            *(uint2*)&A[row][cg * 4] = hv;
            *(uint2*)&A[row][64 + cg * 4] = so;
            float h0, h1f, h2f, h3f;
            bfpair(hv.x, h0, h1f); bfpair(hv.y, h2f, h3f);
            uint2 co;
            co.x = packbf(cn * h0, cn * h1f);
            co.y = packbf(cn * h2f, cn * h3f);
            *(uint2*)&A[row][128 + cg * 4] = co;
            if (cg == 0) csh[row] = cn;
        }
    }
    __syncthreads();

    const int l15 = lane & 15;
    const int q = lane >> 4;
    const int qo = q * 8;

    // ---- phase B: 64x128 GEMM, K=192, epilogue to LDS ht
    {
        const int mt = wv >> 2;
        const int nt0 = (wv & 3) * 2;
        f32x4 acc0 = {0.f, 0.f, 0.f, 0.f};
        f32x4 acc1 = {0.f, 0.f, 0.f, 0.f};
#pragma unroll
        for (int chunk = 0; chunk < 6; chunk++) {
            bf16x8 a = *(const bf16x8*)&A[mt * 16 + l15][chunk * 32 + qo];
            bf16x8 bf0 = *(const bf16x8*)(Bp1 + (((size_t)(chunk * 8 + nt0) * 64 + lane) << 3));
            bf16x8 bf1 = *(const bf16x8*)(Bp1 + (((size_t)(chunk * 8 + nt0 + 1) * 64 + lane) << 3));
            acc0 = __builtin_amdgcn_mfma_f32_16x16x32_bf16(a, bf0, acc0, 0, 0, 0);
            acc1 = __builtin_amdgcn_mfma_f32_16x16x32_bf16(a, bf1, acc1, 0, 0, 0);
        }
#pragma unroll
        for (int ni = 0; ni < 2; ni++) {
            const int col = (nt0 + ni) * 16 + l15;
            const float B3 = bias3[col];
            const float B1 = bias1[col];
            const f32x4 av = ni ? acc1 : acc0;
#pragma unroll
            for (int reg = 0; reg < 4; reg++) {
                const int lrow = mt * 16 + q * 4 + reg;
                ht[lrow][col] = f2bf(elu_f(av[reg] + B3 + csh[lrow] * B1));
            }
        }
    }
    __syncthreads();

    // ---- phase C: 64x192 GEMM, K=128 from ht; split output zu / yb
    {
        const int mt = wv >> 2;
        const int ntb = (wv & 3) * 3;
        f32x4 acc[3] = {};
#pragma unroll
        for (int chunk = 0; chunk < 4; chunk++) {
            bf16x8 a = *(const bf16x8*)&ht[mt * 16 + l15][chunk * 32 + qo];
#pragma unroll
            for (int j = 0; j < 3; j++) {
                bf16x8 b = *(const bf16x8*)(Bp2 + (((size_t)(chunk * 12 + ntb + j) * 64 + lane) << 3));
                acc[j] = __builtin_amdgcn_mfma_f32_16x16x32_bf16(a, b, acc[j], 0, 0, 0);
            }
        }
#pragma unroll
        for (int j = 0; j < 3; j++) {
            const int col = (ntb + j) * 16 + l15;
#pragma unroll
            for (int reg = 0; reg < 4; reg++) {
                const int row = node_base + mt * 16 + q * 4 + reg;
                if (row < N_NODES) {
                    const u16 v = f2bf(acc[j][reg]);
                    if (col < 128) zu[(size_t)row * 128 + col] = v;
                    else           yb[(size_t)row * 64 + (col - 128)] = v;
                }
            }
        }
    }
}

// ---------------------------------------------------------------------------
// Layer-2 gather + fused epilogue (round-7 structure, yb hot set).
// Random reads from yb[N][64] (6.4MB); z,u streamed from zu[N][128].
// h3[i] = elu( z_i + c_i*u_i + sum_e w_e * y[src_e] + b3 + c_i*b1 )
// ---------------------------------------------------------------------------
__global__ __launch_bounds__(256) void gather2_kernel(
    const u16* __restrict__ zu, const u16* __restrict__ yb,
    const int* __restrict__ rowptr, const int2* __restrict__ csr,
    const float* __restrict__ c, const float* __restrict__ bias1,
    const float* __restrict__ bias3, u16* __restrict__ h3) {
    constexpr int CG = 16, EG = 4;
    const int gid = blockIdx.x * 256 + threadIdx.x;
    const int node = gid >> 6;
    if (node >= N_NODES) return;
    const int lane = threadIdx.x & 63;
    const int cg = lane & (CG - 1);
    const int eg = lane >> 4;
    const int beg = rowptr[node];
    const int end = rowptr[node + 1];

    float a0 = 0.f, a1 = 0.f, a2 = 0.f, a3 = 0.f;
    float b0 = 0.f, b1 = 0.f, b2 = 0.f, b3 = 0.f;

    int p = beg + eg;
    for (; p + EG < end; p += 2 * EG) {
        int2 e0 = csr[p];
        int2 e1 = csr[p + EG];
        float w0 = __int_as_float(e0.y);
        float w1 = __int_as_float(e1.y);
        uint2 v0 = ((const uint2*)(yb + (size_t)e0.x * 64))[cg];
        uint2 v1 = ((const uint2*)(yb + (size_t)e1.x * 64))[cg];
        float f0, f1, f2, f3, g0, g1, g2, g3;
        bfpair(v0.x, f0, f1); bfpair(v0.y, f2, f3);
        bfpair(v1.x, g0, g1); bfpair(v1.y, g2, g3);
        a0 += w0 * f0; a1 += w0 * f1; a2 += w0 * f2; a3 += w0 * f3;
        b0 += w1 * g0; b1 += w1 * g1; b2 += w1 * g2; b3 += w1 * g3;
    }
    if (p < end) {
        int2 e0 = csr[p];
        float w0 = __int_as_float(e0.y);
        uint2 v0 = ((const uint2*)(yb + (size_t)e0.x * 64))[cg];
        float f0, f1, f2, f3;
        bfpair(v0.x, f0, f1); bfpair(v0.y, f2, f3);
        a0 += w0 * f0; a1 += w0 * f1; a2 += w0 * f2; a3 += w0 * f3;
    }
    a0 += b0; a1 += b1; a2 += b2; a3 += b3;

#pragma unroll
    for (int off = 32; off >= CG; off >>= 1) {
        a0 += __shfl_xor(a0, off);
        a1 += __shfl_xor(a1, off);
        a2 += __shfl_xor(a2, off);
        a3 += __shfl_xor(a3, off);
    }

    if (lane < CG) {
        const float cn = c[node];
        const u16* zr = zu + (size_t)node * 128;
        uint2 zv = ((const uint2*)zr)[cg];
        uint2 uv = ((const uint2*)(zr + 64))[cg];
        float z0, z1, z2, z3, u0, u1, u2, u3;
        bfpair(zv.x, z0, z1); bfpair(zv.y, z2, z3);
        bfpair(uv.x, u0, u1); bfpair(uv.y, u2, u3);
        const float4 b3v = *(const float4*)(bias3 + cg * 4);
        const float4 b1v = *(const float4*)(bias1 + cg * 4);
        float o0 = elu_f(z0 + cn * u0 + a0 + b3v.x + cn * b1v.x);
        float o1 = elu_f(z1 + cn * u1 + a1 + b3v.y + cn * b1v.y);
        float o2 = elu_f(z2 + cn * u2 + a2 + b3v.z + cn * b1v.z);
        float o3 = elu_f(z3 + cn * u3 + a3 + b3v.w + cn * b1v.w);
        uint2 o;
        o.x = packbf(o0, o1);
        o.y = packbf(o2, o3);
        ((uint2*)h3)[(size_t)node * CG + cg] = o;
    }
}

// ---------------------------------------------------------------------------
// out[g, :] = max over nodes of graph g of h[:, :64] (bf16 in, fp32 out)
// ---------------------------------------------------------------------------
__global__ void pool_kernel(const u16* __restrict__ h,
                            const int* __restrict__ batch,
                            float* __restrict__ out) {
    const int g = blockIdx.x;
    const int tid = threadIdx.x;
    int lo = 0, hi = N_NODES;
    while (lo < hi) { int mid = (lo + hi) >> 1; if (batch[mid] < g) lo = mid + 1; else hi = mid; }
    const int beg = lo;
    lo = beg; hi = N_NODES;
    while (lo < hi) { int mid = (lo + hi) >> 1; if (batch[mid] < g + 1) lo = mid + 1; else hi = mid; }
    const int end = lo;

    __shared__ float red[256];
    const int col = tid & 63;
    const int rg = tid >> 6;
    float m = -3.0e38f;
    for (int r = beg + rg; r < end; r += 4) m = fmaxf(m, bf2f(h[(size_t)r * 64 + col]));
    red[tid] = m;
    __syncthreads();
    if (tid < 64) {
        m = fmaxf(fmaxf(red[tid], red[tid + 64]), fmaxf(red[tid + 128], red[tid + 192]));
        out[g * 64 + tid] = m;
    }
}

extern "C" void kernel_launch(void* const* d_in, const int* in_sizes, int n_in,
                              void* d_out, int out_size, void* d_ws, size_t ws_size,
                              hipStream_t stream) {
    const float* x = (const float*)d_in[0];
    const int* ei = (const int*)d_in[1];
    const float* ea = (const float*)d_in[2];
    const int* batch = (const int*)d_in[3];
    const float* wfc = (const float*)d_in[4];
    const float* bfc = (const float*)d_in[5];
    const float* w1_0 = (const float*)d_in[6];
    const float* b1_0 = (const float*)d_in[7];
    const float* w2_0 = (const float*)d_in[8];
    const float* w3_0 = (const float*)d_in[9];
    const float* b3_0 = (const float*)d_in[10];
    const float* w1_1 = (const float*)d_in[11];
    const float* b1_1 = (const float*)d_in[12];
    const float* w2_1 = (const float*)d_in[13];
    const float* w3_1 = (const float*)d_in[14];
    const float* b3_1 = (const float*)d_in[15];
    const float* w1_2 = (const float*)d_in[16];
    const float* b1_2 = (const float*)d_in[17];
    const float* w2_2 = (const float*)d_in[18];
    const float* w3_2 = (const float*)d_in[19];
    const float* b3_2 = (const float*)d_in[20];
    float* out = (float*)d_out;

    char* ws = (char*)d_ws;
    float* ew      = (float*)(ws);                 // E f32      3.2 MB
    float* c       = (float*)(ws + 3200000);       // N f32
    int*   rowptr  = (int*)  (ws + 3800000);       // N+1 int
    int2*  csr     = (int2*) (ws + 4000128);       // E int2     6.4 MB
    u16*   xb      = (u16*)  (ws + 10400128);      // N*64 bf16  6.4 MB
    u32*   partial = (u32*)  (ws + 16800128);      // 256*12500 u32 = 12.8 MB
    u16*   dst16   = (u16*)  (ws + 29600128);      // E u16      1.6 MB
    u32*   degpack = (u32*)  (ws + 31600128);      // 100 KB
    u16*   h1      = (u16*)  (ws + 42400128);      // N*64 bf16  6.4 MB
    u16*   zu      = (u16*)  (ws + 48800128);      // N*128 bf16 12.8 MB
    u16*   yb      = (u16*)  (ws + 61600128);      // N*64 bf16  6.4 MB
    u16*   bp0     = (u16*)  (ws + 68000128);      // 24 KB packed weights L0
    u16*   bp1     = (u16*)  (ws + 68024704);      // 48 KB L1
    u16*   bp2     = (u16*)  (ws + 68073856);      // 48 KB L2 wide
    int* blk_sums  = (int*)  (ws + 68123008);
    int* blk_offs  = (int*)  (ws + 68123520);
    // aliases into regions dead at time of use:
    u32* prefpack = (u32*)zu;   // 12.8 MB, dead before fused_l1 writes zu
    u16* h3 = xb;               // N*64 bf16 (xb dead after fused_l0)

    // fused prep: ew + conv_x + pack_w in one launch
    prep_kernel<<<6280, 256, 0, stream>>>(ea, wfc, bfc, ei, ew, dst16, x, xb,
                                          w3_0, w1_0, w2_0, w3_1, w1_1, w2_1,
                                          w3_2, w1_2, w2_2, bp0, bp1, bp2);
    deg_hist_kernel<<<HCHUNKS * 2, 256, 0, stream>>>(dst16, partial);
    scan_chunks_kernel<<<TS_BPH * 2, 256, 0, stream>>>(partial, prefpack, degpack);
    scan1_kernel<<<SCAN_NB, 256, 0, stream>>>(degpack, rowptr, blk_sums);
    scan2_kernel<<<1, 128, 0, stream>>>(blk_sums, blk_offs, rowptr);
    scan3_kernel<<<(N_NODES + 255) / 256, 256, 0, stream>>>(rowptr, blk_offs);
    place_kernel<<<HCHUNKS * NPASS, 256, 0, stream>>>(ei, ew, dst16, rowptr, prefpack, csr);

    const int RB = (N_NODES + 63) / 64;           // 782 row-blocks
    const int GBLK = (N_NODES * 64 + 255) / 256;  // one wave per node

    // layer 0: fused gather + GEMM
    fused_l0<<<RB, 1024, 0, stream>>>(xb, rowptr, csr, bp0, b1_0, b3_0, c, h1);

    // layer 1 + layer-2 wide GEMM: fused gather + GEMM1 + GEMM2
    fused_l1<<<RB, 1024, 0, stream>>>(h1, rowptr, csr, bp1, bp2, b1_1, b3_1, zu, yb);

    // layer 2 gather in output space + fused epilogue
    gather2_kernel<<<GBLK, 256, 0, stream>>>(zu, yb, rowptr, csr, c, b1_2, b3_2, h3);

    // global max pool
    pool_kernel<<<NUM_GRAPHS_, 256, 0, stream>>>(h3, batch, out);
}